// Round 3
// baseline (159.462 us; speedup 1.0000x reference)
//
#include <hip/hip_runtime.h>
#include <math.h>

#define G      7
#define NBOX   98
#define CH     30
#define RAWF   1470
#define BATCH  8192
#define WPB    4                 // waves (= batches) per block

// Within-wave LDS visibility: all lanes' outstanding DS ops complete.
// "memory" clobber stops the compiler reordering LDS accesses across it.
#define WAVE_SYNC() asm volatile("s_waitcnt lgkmcnt(0)" ::: "memory")

__device__ __forceinline__ float sigmoidf_(float x) {
    return 1.0f / (1.0f + expf(-x));
}

__global__ __launch_bounds__(64 * WPB) void yolo_nms_kernel(
    const float* __restrict__ p,
    float* __restrict__ out_boxes,   // [B,98,4]
    float* __restrict__ out_scores,  // [B,98]
    float* __restrict__ out_labels,  // [B,98]
    float* __restrict__ out_keep)    // [B,98]
{
#pragma clang fp contract(off)
    // Per-wave private arena: raw[1472] (staged input, later aliased by the
    // sorted-box arrays) + sc[100] (scores for ranking, -1 = invalid/pad).
    __shared__ __align__(16) float arena[WPB][1572];

    const int lane = threadIdx.x & 63;
    const int wv   = threadIdx.x >> 6;
    const int b    = blockIdx.x * WPB + wv;

    float*  raw   = arena[wv];
    float*  sc    = arena[wv] + 1472;          // 5888 B offset, 16B aligned
    float4* sbox  = (float4*)raw;              // sorted boxes   [98]
    float2* smeta = (float2*)(raw + 392);      // (area, label)  [98]

    // ---- stage input to LDS (coalesced float2) ----
    const float2* src = (const float2*)(p + (size_t)b * RAWF);
    float2* raw2 = (float2*)raw;
    for (int k = lane; k < RAWF / 2; k += 64) raw2[k] = src[k];
    WAVE_SYNC();

    // ---- decode 2 boxes per lane (t = lane, lane+64); write NMS-independent outputs ----
    float4 bb[2]; float s[2]; float area[2]; int lb[2]; bool vld[2];
    #pragma unroll
    for (int u = 0; u < 2; ++u) {
        const int t = lane + 64 * u;
        s[u] = -1.0f; vld[u] = false; lb[u] = 0;
        bb[u] = make_float4(0.f, 0.f, 0.f, 0.f); area[u] = 0.0f;
        if (t < NBOX) {
            const int cell = t >> 1, j = t & 1;
            const int r = cell / G, c = cell - r * G;
            const float2* q2 = (const float2*)(raw + cell * CH);
            float2 xy = q2[2 * j];
            float2 wh = q2[2 * j + 1];
            float gx = (sigmoidf_(xy.x) + (float)c) / 7.0f;
            float gy = (sigmoidf_(xy.y) + (float)r) / 7.0f;
            float hx = wh.x * 0.5f, hy = wh.y * 0.5f;
            bb[u] = make_float4(gx - hx, gy - hy, gx + hx, gy + hy);
            area[u] = fmaxf(bb[u].z - bb[u].x, 0.0f) * fmaxf(bb[u].w - bb[u].y, 0.0f);
            s[u] = sigmoidf_(raw[cell * CH + 8 + j]);
            vld[u] = (s[u] > 0.5f);
            float2 c0 = q2[5];
            float best = c0.x; int bi = 0;
            if (c0.y > best) { best = c0.y; bi = 1; }
            #pragma unroll
            for (int k2 = 1; k2 < 10; ++k2) {
                float2 cv = q2[5 + k2];
                if (cv.x > best) { best = cv.x; bi = 2 * k2; }
                if (cv.y > best) { best = cv.y; bi = 2 * k2 + 1; }
            }
            lb[u] = bi + 1;
            ((float4*)(out_boxes + (size_t)b * (NBOX * 4)))[t] = bb[u];
            out_scores[(size_t)b * NBOX + t] = s[u];
            out_labels[(size_t)b * NBOX + t] = (float)lb[u];
        }
    }

    // ---- V = number of valid boxes (all valid sort strictly before all invalid) ----
    const int V = __popcll(__ballot(vld[0])) + __popcll(__ballot(vld[1]));

    // ---- publish masked scores (invalid/pad -> -1, never outranks valid >0.5) ----
    sc[lane] = vld[0] ? s[0] : -1.0f;
    if (lane + 64 < 100) sc[lane + 64] = vld[1] ? s[1] : -1.0f;
    WAVE_SYNC();

    // ---- stable descending rank among valid (matches stable argsort(-scores) prefix) ----
    const float4* sc4 = (const float4*)sc;
    int rk[2] = {0, 0};
    for (int j4 = 0; j4 < 25; ++j4) {
        const float4 v = sc4[j4];
        const int j = j4 * 4;
        rk[0] += (v.x > s[0]) || ((v.x == s[0]) && (j + 0 < lane));
        rk[0] += (v.y > s[0]) || ((v.y == s[0]) && (j + 1 < lane));
        rk[0] += (v.z > s[0]) || ((v.z == s[0]) && (j + 2 < lane));
        rk[0] += (v.w > s[0]) || ((v.w == s[0]) && (j + 3 < lane));
        rk[1] += (v.x > s[1]) || ((v.x == s[1]) && (j + 0 < lane + 64));
        rk[1] += (v.y > s[1]) || ((v.y == s[1]) && (j + 1 < lane + 64));
        rk[1] += (v.z > s[1]) || ((v.z == s[1]) && (j + 2 < lane + 64));
        rk[1] += (v.w > s[1]) || ((v.w == s[1]) && (j + 3 < lane + 64));
    }
    WAVE_SYNC();   // rank reads of sc done before sbox/smeta overwrite raw region

    // ---- write sorted boxes (raw is dead; sbox/smeta alias it) ----
    if (vld[0]) { sbox[rk[0]] = bb[0]; smeta[rk[0]] = make_float2(area[0], (float)lb[0]); }
    if (vld[1]) { sbox[rk[1]] = bb[1]; smeta[rk[1]] = make_float2(area[1], (float)lb[1]); }
    WAVE_SYNC();

    // ---- fused ballot-NMS: lane j owns sorted box j; serial greedy over i ----
    const float4 mb = sbox[lane];      // garbage for lane >= V: masked below
    const float2 mm = smeta[lane];
    unsigned long long k0 = 0ull, k1 = 0ull;
    // exact division-free predicate: RN(inter/uc) > 0.3f <=> inter > (0.3f+2^-26)*uc (exact in f64)
    const double UD = (double)0.3f + 0x1p-26;
    if (V <= 64) {
        #pragma unroll 2
        for (int i = 0; i < V; ++i) {
            const float4 bi = sbox[i];     // uniform-address broadcast reads
            const float2 mi = smeta[i];
            float w = fmaxf(fminf(bi.z, mb.z) - fmaxf(bi.x, mb.x), 0.0f);
            float h = fmaxf(fminf(bi.w, mb.w) - fmaxf(bi.y, mb.y), 0.0f);
            float inter = w * h;
            float uc = fmaxf(mi.x + mm.x - inter, 1e-9f);
            bool hit = ((double)inter > UD * (double)uc) && (mi.y == mm.y);
            unsigned long long bmm = __ballot(hit);
            if ((bmm & k0 & ((1ull << i) - 1ull)) == 0ull) k0 |= 1ull << i;
        }
    } else {
        // rare (~0.1% of batches): V in (64, 98]
        const float4 mb2 = sbox[lane + 64];    // safe in-arena garbage, masked
        const float2 mm2 = smeta[lane + 64];
        for (int i = 0; i < V; ++i) {
            const float4 bi = sbox[i];
            const float2 mi = smeta[i];
            float w1 = fmaxf(fminf(bi.z, mb.z) - fmaxf(bi.x, mb.x), 0.0f);
            float h1 = fmaxf(fminf(bi.w, mb.w) - fmaxf(bi.y, mb.y), 0.0f);
            float i1 = w1 * h1;
            float u1 = fmaxf(mi.x + mm.x - i1, 1e-9f);
            bool hit1 = ((double)i1 > UD * (double)u1) && (mi.y == mm.y);
            float w2 = fmaxf(fminf(bi.z, mb2.z) - fmaxf(bi.x, mb2.x), 0.0f);
            float h2 = fmaxf(fminf(bi.w, mb2.w) - fmaxf(bi.y, mb2.y), 0.0f);
            float i2 = w2 * h2;
            float u2 = fmaxf(mi.x + mm2.x - i2, 1e-9f);
            bool hit2 = ((double)i2 > UD * (double)u2) && (mi.y == mm2.y);
            unsigned long long m0 = __ballot(hit1);
            unsigned long long m1 = __ballot(hit2);
            unsigned long long mask0 = (i < 64) ? ((1ull << i) - 1ull) : ~0ull;
            unsigned long long mask1 = (i < 64) ? 0ull : ((1ull << (i - 64)) - 1ull);
            if (((m0 & k0 & mask0) | (m1 & k1 & mask1)) == 0ull) {
                if (i < 64) k0 |= 1ull << i;
                else        k1 |= 1ull << (i - 64);
            }
        }
    }

    // ---- keep[t]: lane knows its own rank -> no scatter ----
    float kv0 = 0.0f, kv1 = 0.0f;
    if (vld[0]) {
        unsigned long long kk = (rk[0] < 64) ? k0 : k1;
        kv0 = (float)((kk >> (rk[0] & 63)) & 1ull);
    }
    if (vld[1]) {
        unsigned long long kk = (rk[1] < 64) ? k0 : k1;
        kv1 = (float)((kk >> (rk[1] & 63)) & 1ull);
    }
    out_keep[(size_t)b * NBOX + lane] = kv0;
    if (lane + 64 < NBOX) out_keep[(size_t)b * NBOX + lane + 64] = kv1;
}

extern "C" void kernel_launch(void* const* d_in, const int* in_sizes, int n_in,
                              void* d_out, int out_size, void* d_ws, size_t ws_size,
                              hipStream_t stream) {
    const float* p = (const float*)d_in[0];
    float* out = (float*)d_out;
    float* out_boxes  = out;
    float* out_scores = out + (size_t)BATCH * NBOX * 4;
    float* out_labels = out_scores + (size_t)BATCH * NBOX;
    float* out_keep   = out_labels + (size_t)BATCH * NBOX;

    yolo_nms_kernel<<<BATCH / WPB, 64 * WPB, 0, stream>>>(p, out_boxes, out_scores,
                                                          out_labels, out_keep);
}

// Round 4
// 125.228 us; speedup vs baseline: 1.2734x; 1.2734x over previous
//
#include <hip/hip_runtime.h>
#include <math.h>

#define G      7
#define NBOX   98
#define CH     30
#define RAWF   1470
#define BATCH  8192

// Wave-internal LDS visibility: drain this wave's outstanding DS ops.
// "memory" clobber stops the compiler moving LDS accesses across it.
#define WAVE_SYNC() asm volatile("s_waitcnt lgkmcnt(0)" ::: "memory")

__device__ __forceinline__ float sigmoidf_(float x) {
    return 1.0f / (1.0f + expf(-x));
}
// Broadcast lane i's value to all lanes (i wave-uniform). Pure VALU, no LDS.
__device__ __forceinline__ float rdlanef(float x, int i) {
    return __int_as_float(__builtin_amdgcn_readlane(__float_as_int(x), i));
}

__global__ __launch_bounds__(128, 8) void yolo_nms_kernel(
    const float* __restrict__ p,
    float* __restrict__ out_boxes,   // [B,98,4]
    float* __restrict__ out_scores,  // [B,98]
    float* __restrict__ out_labels,  // [B,98]
    float* __restrict__ out_keep)    // [B,98]
{
#pragma clang fp contract(off)
    // Per-wave small LDS: sorted-box shuffle arrays + compact scores + labels.
    __shared__ __align__(16) float4 sboxS[2][NBOX];   // 2*1568 B
    __shared__ __align__(8)  float2 smetaS[2][NBOX];  // 2*784 B  (area, label)
    __shared__ float cscS[2][100];                    // compacted scores
    __shared__ float clabS[2][52];                    // per-cell label (float)

    const int lane = threadIdx.x & 63;
    const int wv   = threadIdx.x >> 6;
    const int b    = blockIdx.x * 2 + wv;

    float4* sbox  = sboxS[wv];
    float2* smeta = smetaS[wv];
    float*  csc   = cscS[wv];
    float*  clab  = clabS[wv];

    const float* base = p + (size_t)b * RAWF;

    // ---- per-cell class argmax (once per cell, lanes 0..48) ----
    if (lane < 49) {
        const float2* q2 = (const float2*)(base + lane * CH + 10);  // 8B aligned
        float2 c0 = q2[0];
        float best = c0.x; int bi = 0;
        if (c0.y > best) { best = c0.y; bi = 1; }
        #pragma unroll
        for (int k2 = 1; k2 < 10; ++k2) {
            float2 cv = q2[k2];
            if (cv.x > best) { best = cv.x; bi = 2 * k2; }
            if (cv.y > best) { best = cv.y; bi = 2 * k2 + 1; }
        }
        clab[lane] = (float)(bi + 1);
    }

    // ---- decode 2 slots per lane (t = lane, lane+64); direct global reads ----
    float4 bb[2]; float s[2], area[2]; bool vld[2];
    #pragma unroll
    for (int u = 0; u < 2; ++u) {
        const int t = lane + 64 * u;
        s[u] = -1.0f; vld[u] = false; area[u] = 0.0f;
        bb[u] = make_float4(0.f, 0.f, 0.f, 0.f);
        if (t < NBOX) {
            const int cell = t >> 1, j = t & 1;
            const int r = cell / G, c = cell - r * G;
            const float* q = base + cell * CH + j * 4;
            float2 xy = *(const float2*)q;        // tx, ty (8B aligned)
            float2 wh = *(const float2*)(q + 2);  // tw, th
            float conf = base[cell * CH + 8 + j];
            float gx = (sigmoidf_(xy.x) + (float)c) / 7.0f;
            float gy = (sigmoidf_(xy.y) + (float)r) / 7.0f;
            float hx = wh.x * 0.5f, hy = wh.y * 0.5f;
            bb[u] = make_float4(gx - hx, gy - hy, gx + hx, gy + hy);
            area[u] = fmaxf(bb[u].z - bb[u].x, 0.0f) * fmaxf(bb[u].w - bb[u].y, 0.0f);
            s[u] = sigmoidf_(conf);
            vld[u] = (s[u] > 0.5f);
            ((float4*)(out_boxes + (size_t)b * (NBOX * 4)))[t] = bb[u];
            out_scores[(size_t)b * NBOX + t] = s[u];
        }
    }
    WAVE_SYNC();   // clab visible

    // ---- labels out + ballot-compaction of valid scores ----
    float lblf[2] = {0.0f, 0.0f};
    lblf[0] = clab[lane >> 1];
    out_labels[(size_t)b * NBOX + lane] = lblf[0];
    if (lane + 64 < NBOX) {
        lblf[1] = clab[(lane + 64) >> 1];
        out_labels[(size_t)b * NBOX + lane + 64] = lblf[1];
    }

    unsigned long long mk0 = __ballot(vld[0]);
    unsigned long long mk1 = __ballot(vld[1]);
    const int c0 = __popcll(mk0);
    const int V  = c0 + __popcll(mk1);           // valid = prefix of sorted order
    const unsigned long long below = (1ull << lane) - 1ull;
    int ci[2];
    ci[0] = __popcll(mk0 & below);
    ci[1] = c0 + __popcll(mk1 & below);
    if (vld[0]) csc[ci[0]] = s[0];
    if (vld[1]) csc[ci[1]] = s[1];
    WAVE_SYNC();

    // ---- stable descending rank via readlane over compact scores ----
    const float scs  = csc[lane];
    const float scs2 = csc[(lane + 64 < 100) ? lane + 64 : 99];
    int rk[2] = {0, 0};
    const int Vc = (V < 64) ? V : 64;
    for (int jj = 0; jj < Vc; ++jj) {
        float sj = rdlanef(scs, jj);
        rk[0] += (sj > s[0]) || ((sj == s[0]) && (jj < ci[0]));
        rk[1] += (sj > s[1]) || ((sj == s[1]) && (jj < ci[1]));
    }
    for (int jj = 64; jj < V; ++jj) {            // rare: V > 64
        float sj = rdlanef(scs2, jj - 64);
        rk[0] += (sj > s[0]) || ((sj == s[0]) && (jj < ci[0]));
        rk[1] += (sj > s[1]) || ((sj == s[1]) && (jj < ci[1]));
    }

    // ---- push boxes to sorted slots; lane pulls slot 'lane' into registers ----
    if (vld[0]) { sbox[rk[0]] = bb[0]; smeta[rk[0]] = make_float2(area[0], lblf[0]); }
    if (vld[1]) { sbox[rk[1]] = bb[1]; smeta[rk[1]] = make_float2(area[1], lblf[1]); }
    WAVE_SYNC();
    const float4 mb = sbox[lane];
    const float2 mm = smeta[lane];
    const float mlab = (lane < V) ? mm.y : -1.0f;   // sentinel kills garbage hits

    // ---- fused readlane-ballot NMS (mask build + greedy scan in one loop) ----
    unsigned long long k0 = 0ull, k1 = 0ull;
    // exact division-free predicate: RN(inter/uc) > 0.3f <=> inter > (0.3f+2^-26)*uc (exact in f64)
    const double UD = (double)0.3f + 0x1p-26;
    if (V <= 64) {
        for (int i = 0; i < V; ++i) {
            float bx = rdlanef(mb.x, i), by = rdlanef(mb.y, i);
            float bz = rdlanef(mb.z, i), bw = rdlanef(mb.w, i);
            float ba = rdlanef(mm.x, i), bl = rdlanef(mlab, i);
            float w = fmaxf(fminf(bz, mb.z) - fmaxf(bx, mb.x), 0.0f);
            float h = fmaxf(fminf(bw, mb.w) - fmaxf(by, mb.y), 0.0f);
            float inter = w * h;
            float uc = fmaxf(ba + mm.x - inter, 1e-9f);
            bool hit = ((double)inter > UD * (double)uc) && (bl == mlab);
            unsigned long long row = __ballot(hit);
            // k has only bits < i set; row&k != 0 -> suppressed by a kept box
            k0 |= ((row & k0) == 0ull) ? (1ull << i) : 0ull;
        }
    } else {
        // rare (~0.1% of batches): V in (64, 98]
        const int i2c = (lane + 64 < NBOX) ? lane + 64 : NBOX - 1;
        const float4 mb2 = sbox[i2c];
        const float2 mm2 = smeta[i2c];
        const float mlab2 = (lane + 64 < V) ? mm2.y : -1.0f;
        for (int i = 0; i < V; ++i) {
            float bx, by, bz, bw, ba, bl;
            if (i < 64) {
                bx = rdlanef(mb.x, i);  by = rdlanef(mb.y, i);
                bz = rdlanef(mb.z, i);  bw = rdlanef(mb.w, i);
                ba = rdlanef(mm.x, i);  bl = rdlanef(mlab, i);
            } else {
                bx = rdlanef(mb2.x, i - 64);  by = rdlanef(mb2.y, i - 64);
                bz = rdlanef(mb2.z, i - 64);  bw = rdlanef(mb2.w, i - 64);
                ba = rdlanef(mm2.x, i - 64);  bl = rdlanef(mlab2, i - 64);
            }
            float w1 = fmaxf(fminf(bz, mb.z) - fmaxf(bx, mb.x), 0.0f);
            float h1 = fmaxf(fminf(bw, mb.w) - fmaxf(by, mb.y), 0.0f);
            float i1 = w1 * h1;
            float u1 = fmaxf(ba + mm.x - i1, 1e-9f);
            bool hit1 = ((double)i1 > UD * (double)u1) && (bl == mlab);
            float w2 = fmaxf(fminf(bz, mb2.z) - fmaxf(bx, mb2.x), 0.0f);
            float h2 = fmaxf(fminf(bw, mb2.w) - fmaxf(by, mb2.y), 0.0f);
            float i2 = w2 * h2;
            float u2 = fmaxf(ba + mm2.x - i2, 1e-9f);
            bool hit2 = ((double)i2 > UD * (double)u2) && (bl == mlab2);
            unsigned long long row0 = __ballot(hit1);
            unsigned long long row1 = __ballot(hit2);
            if (((row0 & k0) | (row1 & k1)) == 0ull) {
                if (i < 64) k0 |= 1ull << i;
                else        k1 |= 1ull << (i - 64);
            }
        }
    }

    // ---- keep: lane knows its own ranks; no scatter needed ----
    float kv0 = 0.0f, kv1 = 0.0f;
    if (vld[0]) kv0 = (float)((((rk[0] < 64) ? k0 : k1) >> (rk[0] & 63)) & 1ull);
    if (vld[1]) kv1 = (float)((((rk[1] < 64) ? k0 : k1) >> (rk[1] & 63)) & 1ull);
    out_keep[(size_t)b * NBOX + lane] = kv0;
    if (lane + 64 < NBOX) out_keep[(size_t)b * NBOX + lane + 64] = kv1;
}

extern "C" void kernel_launch(void* const* d_in, const int* in_sizes, int n_in,
                              void* d_out, int out_size, void* d_ws, size_t ws_size,
                              hipStream_t stream) {
    const float* p = (const float*)d_in[0];
    float* out = (float*)d_out;
    float* out_boxes  = out;
    float* out_scores = out + (size_t)BATCH * NBOX * 4;
    float* out_labels = out_scores + (size_t)BATCH * NBOX;
    float* out_keep   = out_labels + (size_t)BATCH * NBOX;

    yolo_nms_kernel<<<BATCH / 2, 128, 0, stream>>>(p, out_boxes, out_scores,
                                                   out_labels, out_keep);
}